// Round 7
// baseline (153.533 us; speedup 1.0000x reference)
//
#include <hip/hip_runtime.h>

typedef __bf16   bf16x8 __attribute__((ext_vector_type(8)));
typedef float    f32x4  __attribute__((ext_vector_type(4)));
typedef float    f32x2  __attribute__((ext_vector_type(2)));
typedef uint32_t u32x4  __attribute__((ext_vector_type(4)));

constexpr int N_ = 16384;
constexpr int D_ = 16;
constexpr int P_ = 8;
constexpr int H_ = 128;
constexpr int M_ = 50;

// pack two f32 -> one bf16x2 register word (round-half-up; 3 VALU ops)
__device__ __forceinline__ uint32_t pk_bf16(float a, float b) {
    uint32_t ua = __builtin_bit_cast(uint32_t, a) + 0x8000u;
    uint32_t ub = __builtin_bit_cast(uint32_t, b) + 0x8000u;
    return __builtin_amdgcn_perm(ub, ua, 0x07060302u);   // [a.hi16 | b.hi16]
}
__device__ __forceinline__ uint32_t pk_relu_bf16(float a, float b) {
    return pk_bf16(fmaxf(a, 0.0f), fmaxf(b, 0.0f));
}

// R7: TIME-split. Z never feeds back into X, so wave 1 pre-rolls X through
// steps 0..24 (cheap fma chain; noise re-reads hit L2/L3) and runs steps
// 25..49 fully independently of wave 0 (steps 0..24). No per-step barriers;
// two independent MFMA streams per SIMD -> cross-wave MFMA/VALU overlap.
// To fit 2 waves/SIMD (<=256 regs/wave), W2 lives in a 32KB LDS table
// (per-lane fragment layout, ds_read_b128 immediate offsets, 2-way bank
// aliasing = free). V partials merge via LDS once at the end.
__global__ __launch_bounds__(128, 2)
void sde_fused(const float* __restrict__ X0,
               const float* __restrict__ V0,
               const float* __restrict__ Yobs,
               const float* __restrict__ noise,
               const float* __restrict__ W1, const float* __restrict__ b1,
               const float* __restrict__ W2, const float* __restrict__ b2,
               const float* __restrict__ W3, const float* __restrict__ b3,
               float* __restrict__ out)
{
    __shared__ u32x4 w2lds[8][4][64];   // 32 KB: [ct][kt][lane] fragment
    __shared__ float vsh[2][16];

    const int tid  = threadIdx.x;
    const int wv   = tid >> 6;      // wave 0: steps 0..24, wave 1: steps 25..49
    const int lane = tid & 63;
    const int n    = lane & 15;     // particle within tile
    const int q    = lane >> 4;     // quad
    const int gr   = blockIdx.x * 16 + n;

    const float dt   = 0.02f;
    const float sqdt = 0.1414213562373095f;

    // ---- W2 -> LDS table (each wave populates 16 of the 32 fragments) ----
#pragma unroll
    for (int i = 0; i < 16; ++i) {
        int idx = wv * 16 + i;
        int ct = idx >> 2, kt = idx & 3;
        u32x4 u;
#pragma unroll
        for (int w = 0; w < 4; ++w) {
            int h0 = (kt * 2 + (w >> 1)) * 16 + q * 4 + (w & 1) * 2;
            u[w] = pk_bf16(W2[h0 * H_ + ct * 16 + n],
                           W2[(h0 + 1) * H_ + ct * 16 + n]);
        }
        w2lds[ct][kt][lane] = u;
    }

    // ---- register weights: W1, W3, biases ----
    bf16x8 w1f[8];
#pragma unroll
    for (int ct = 0; ct < 8; ++ct) {
        u32x4 u;
        u[0] = pk_bf16(W1[(1 + q * 4 + 0) * H_ + ct * 16 + n],
                       W1[(1 + q * 4 + 1) * H_ + ct * 16 + n]);
        u[1] = pk_bf16(W1[(1 + q * 4 + 2) * H_ + ct * 16 + n],
                       W1[(1 + q * 4 + 3) * H_ + ct * 16 + n]);
        u[2] = pk_bf16(W1[(17 + q * 2 + 0) * H_ + ct * 16 + n],
                       W1[(17 + q * 2 + 1) * H_ + ct * 16 + n]);
        u[3] = (q == 0) ? pk_bf16(b1[ct * 16 + n], W1[ct * 16 + n]) : 0u;
        w1f[ct] = __builtin_bit_cast(bf16x8, u);
    }
    bf16x8 w3f[4];
#pragma unroll
    for (int kt = 0; kt < 4; ++kt) {
        u32x4 u;
#pragma unroll
        for (int w = 0; w < 4; ++w) {
            int h0 = (kt * 2 + (w >> 1)) * 16 + q * 4 + (w & 1) * 2;
            u[w] = pk_bf16(W3[h0 * D_ + n], W3[(h0 + 1) * D_ + n]);
        }
        w3f[kt] = __builtin_bit_cast(bf16x8, u);
    }
    f32x4 b2r[8];
#pragma unroll
    for (int ct = 0; ct < 8; ++ct)
#pragma unroll
        for (int r = 0; r < 4; ++r) b2r[ct][r] = b2[ct * 16 + q * 4 + r];
    f32x4 b3r;
#pragma unroll
    for (int r = 0; r < 4; ++r) b3r[r] = b3[q * 4 + r];

    // ---- state ----
    f32x4 x = *(const f32x4*)&X0[gr * D_ + q * 4];
    f32x2 y2 = *(const f32x2*)&Yobs[gr * P_ + q * 2];
    const uint32_t yw = pk_bf16(y2[0], y2[1]);

    const float* npb = noise + (size_t)gr * D_ + q * 4;
    const size_t stp = (size_t)N_ * D_;

    // wave 1: pre-roll X through steps 0..24 (no MLP; loads mostly L2/L3 hits)
    if (wv == 1) {
#pragma unroll 5
        for (int m = 0; m < 25; ++m) {
            f32x4 ee = *(const f32x4*)(npb + (size_t)m * stp);
#pragma unroll
            for (int r = 0; r < 4; ++r)
                x[r] = fmaf(x[r], 0.98f, sqdt * ee[r]);
        }
    }

    __syncthreads();   // w2lds ready (placed after pre-roll to overlap)

    const float* base = npb + (size_t)(wv * 25) * stp;
    f32x4 e0 = *(const f32x4*)(base);
    f32x4 e1 = *(const f32x4*)(base + stp);
    float t = wv ? 0.5f : 0.0f;
    float vacc = 0.0f;

    for (int m = 0; m < 25; ++m) {
        int mp = (m + 2 < 25) ? (m + 2) : 24;
        f32x4 e2 = *(const f32x4*)(base + (size_t)mp * stp);

        // ---- layer 1 B fragment: [X(4) | Y(2) | one | t] ----
        u32x4 au;
        au[0] = pk_bf16(x[0], x[1]);
        au[1] = pk_bf16(x[2], x[3]);
        au[2] = yw;
        au[3] = (q == 0) ? pk_bf16(1.0f, t) : 0u;
        bf16x8 a0 = __builtin_bit_cast(bf16x8, au);

        f32x4 h1c[8];
#pragma unroll
        for (int ct = 0; ct < 8; ++ct)
            h1c[ct] = __builtin_amdgcn_mfma_f32_16x16x32_bf16(
                w1f[ct], a0, (f32x4){0.f, 0.f, 0.f, 0.f}, 0, 0, 0);

        bf16x8 h1b[4];
#pragma unroll
        for (int kt = 0; kt < 4; ++kt) {
            u32x4 u;
            u[0] = pk_relu_bf16(h1c[2 * kt][0], h1c[2 * kt][1]);
            u[1] = pk_relu_bf16(h1c[2 * kt][2], h1c[2 * kt][3]);
            u[2] = pk_relu_bf16(h1c[2 * kt + 1][0], h1c[2 * kt + 1][1]);
            u[3] = pk_relu_bf16(h1c[2 * kt + 1][2], h1c[2 * kt + 1][3]);
            h1b[kt] = __builtin_bit_cast(bf16x8, u);
        }

        // ---- layer 2: W2 fragments streamed from LDS ----
        f32x4 h2c[8];
#pragma unroll
        for (int ct = 0; ct < 8; ++ct) {
            bf16x8 f0 = __builtin_bit_cast(bf16x8, w2lds[ct][0][lane]);
            bf16x8 f1 = __builtin_bit_cast(bf16x8, w2lds[ct][1][lane]);
            bf16x8 f2 = __builtin_bit_cast(bf16x8, w2lds[ct][2][lane]);
            bf16x8 f3 = __builtin_bit_cast(bf16x8, w2lds[ct][3][lane]);
            f32x4 cc = b2r[ct];
            cc = __builtin_amdgcn_mfma_f32_16x16x32_bf16(f0, h1b[0], cc, 0, 0, 0);
            cc = __builtin_amdgcn_mfma_f32_16x16x32_bf16(f1, h1b[1], cc, 0, 0, 0);
            cc = __builtin_amdgcn_mfma_f32_16x16x32_bf16(f2, h1b[2], cc, 0, 0, 0);
            cc = __builtin_amdgcn_mfma_f32_16x16x32_bf16(f3, h1b[3], cc, 0, 0, 0);
            h2c[ct] = cc;
        }

        bf16x8 h2b[4];
#pragma unroll
        for (int kt = 0; kt < 4; ++kt) {
            u32x4 u;
            u[0] = pk_relu_bf16(h2c[2 * kt][0], h2c[2 * kt][1]);
            u[1] = pk_relu_bf16(h2c[2 * kt][2], h2c[2 * kt][3]);
            u[2] = pk_relu_bf16(h2c[2 * kt + 1][0], h2c[2 * kt + 1][1]);
            u[3] = pk_relu_bf16(h2c[2 * kt + 1][2], h2c[2 * kt + 1][3]);
            h2b[kt] = __builtin_bit_cast(bf16x8, u);
        }

        // ---- layer 3 ----
        f32x4 za = __builtin_amdgcn_mfma_f32_16x16x32_bf16(w3f[0], h2b[0], b3r, 0, 0, 0);
        za = __builtin_amdgcn_mfma_f32_16x16x32_bf16(w3f[1], h2b[1], za, 0, 0, 0);
        f32x4 zb = __builtin_amdgcn_mfma_f32_16x16x32_bf16(
            w3f[2], h2b[2], (f32x4){0.f, 0.f, 0.f, 0.f}, 0, 0, 0);
        zb = __builtin_amdgcn_mfma_f32_16x16x32_bf16(w3f[3], h2b[3], zb, 0, 0, 0);

        // ---- V partial + X update ----
#pragma unroll
        for (int r = 0; r < 4; ++r) {
            float z  = za[r] + zb[r];
            float wn = sqdt * e0[r];
            vacc = fmaf(z, wn, fmaf(0.01f * z, z, vacc));   // z*wn + dt/2*z^2
            x[r] = fmaf(x[r], 0.98f, wn);                   // (1-dt)*x + wn
        }

        e0 = e1; e1 = e2;
        t += dt;
    }

    // ---- merge: per-wave V partial -> LDS, wave 1 writes outputs ----
    float part = vacc;
    part += __shfl_xor(part, 16);
    part += __shfl_xor(part, 32);
    if (q == 0) vsh[wv][n] = part;
    __syncthreads();

    if (wv == 1) {
        *(f32x4*)&out[gr * D_ + q * 4] = x;
        if (q == 0) out[N_ * D_ + gr] = V0[gr] + vsh[0][n] + vsh[1][n];
    }
}

extern "C" void kernel_launch(void* const* d_in, const int* in_sizes, int n_in,
                              void* d_out, int out_size, void* d_ws, size_t ws_size,
                              hipStream_t stream)
{
    const float* X0 = (const float*)d_in[0];
    const float* V0 = (const float*)d_in[1];
    const float* Y  = (const float*)d_in[2];
    const float* nz = (const float*)d_in[3];
    const float* W1 = (const float*)d_in[4];
    const float* b1 = (const float*)d_in[5];
    const float* W2 = (const float*)d_in[6];
    const float* b2 = (const float*)d_in[7];
    const float* W3 = (const float*)d_in[8];
    const float* b3 = (const float*)d_in[9];
    float* out = (float*)d_out;

    sde_fused<<<N_ / 16, 128, 0, stream>>>(X0, V0, Y, nz, W1, b1, W2, b2, W3, b3, out);
}